// Round 2
// baseline (748.473 us; speedup 1.0000x reference)
//
#include <hip/hip_runtime.h>
#include <stdint.h>
#include <stddef.h>

// ---------------------------------------------------------------------------
// Fused pre-LN transformer block, B=8192 T=16 C=256 H=4 HS=64 FF=1024.
// bf16 MFMA (16x16x32) everywhere, fp32 accumulation, fp32 residual path.
// One WG = 128 rows (8 batch elems, 1 per wave for attention), 512 thr = 8 waves.
// ---------------------------------------------------------------------------

#define NTH 512

using f32x4 = __attribute__((ext_vector_type(4))) float;
using s16x8 = __attribute__((ext_vector_type(8))) short;

__device__ __forceinline__ uint16_t f2bf(float f) {
  union { float f; uint32_t u; } v; v.f = f;
  uint32_t r = v.u + 0x7FFF + ((v.u >> 16) & 1);  // RNE
  return (uint16_t)(r >> 16);
}

// ------------------------- weight conversion kernels -----------------------
// qkvt[h][n][k] bf16, n in [0,192): 0-63 q, 64-127 k, 128-191 v; k in [0,256)
__global__ void cvt_qkv(const float* __restrict__ Wq, const float* __restrict__ Wk,
                        const float* __restrict__ Wv, uint16_t* __restrict__ dst) {
  int tid = blockIdx.x * 256 + threadIdx.x;
  if (tid >= 4 * 192 * 256) return;
  int h = tid / (192 * 256);
  int r = tid % (192 * 256);
  int n = r / 256, k = r % 256;
  int comp = n >> 6, d = n & 63;
  const float* src = (comp == 0) ? Wq : ((comp == 1) ? Wk : Wv);
  dst[tid] = f2bf(src[(size_t)h * 256 * 64 + (size_t)k * 64 + d]);
}

// dst[n*K + k] = W[k*N + n]   (bf16 transposed, k-contiguous)
__global__ void cvt_t(const float* __restrict__ W, uint16_t* __restrict__ dst,
                      int K, int N) {
  int tid = blockIdx.x * 256 + threadIdx.x;
  if (tid >= K * N) return;
  int n = tid / K, k = tid % K;
  dst[tid] = f2bf(W[(size_t)k * N + n]);
}

// ------------------------------ LDS layout ---------------------------------
// h buf   [128][264] bf16 stride 528B  (LN1 out h1, later LN2 out h2)
// staging [256][40]  bf16 stride 80B   (B-operand K-step tiles)
// scratch union:
//   attention: Q[128][72]b16(144B rows) K[128][72] VT[8][64][24]b16(48B rows)
//              P[8 waves][16][40]b16(80B rows)
//   LN2:       STATS[128][8] f32  (overlays P)
//   FF:        U[128][264] bf16 stride 528B (overlays whole scratch)
#define OFF_H     0
#define OFF_STG   67584
#define OFF_SCR   88064
#define OFF_Q     (OFF_SCR + 0)
#define OFF_K     (OFF_SCR + 18432)
#define OFF_VT    (OFF_SCR + 36864)
#define OFF_P     (OFF_SCR + 61440)
#define OFF_STATS (OFF_SCR + 61440)
#define OFF_U     (OFF_SCR + 0)
#define LDS_BYTES 159744

__device__ __forceinline__ void stageB(const uint16_t* __restrict__ src, int strideK,
                                       int kk0, int nrows, char* stg, int tid) {
  // copy nrows rows x 32 bf16 (64B) from src[n][kk0..kk0+32) to stg rows of 80B
  int chunks = nrows * 4;
  for (int idx = tid; idx < chunks; idx += NTH) {
    int n = idx >> 2, o = idx & 3;
    uint4 v = *(const uint4*)(src + (size_t)n * strideK + kk0 + o * 8);
    *(uint4*)(stg + n * 80 + o * 16) = v;
  }
}

__global__ __launch_bounds__(NTH, 2) void block_fused(
    const float* __restrict__ xg,
    const uint16_t* __restrict__ qkvt, const uint16_t* __restrict__ wot,
    const uint16_t* __restrict__ w1t, const uint16_t* __restrict__ w2t,
    const float* __restrict__ bo, const float* __restrict__ b1,
    const float* __restrict__ b2, const float* __restrict__ g1,
    const float* __restrict__ be1, const float* __restrict__ g2,
    const float* __restrict__ be2, float* __restrict__ outg) {
  __shared__ __align__(16) char lds[LDS_BYTES];
  const int tid = threadIdx.x;
  const int wave = tid >> 6, lane = tid & 63;
  const int quad = lane >> 4, l15 = lane & 15;
  const int wr = wave >> 2, wc = wave & 3;   // 2x4 wave grid for GEMMs
  const int row0 = blockIdx.x * 128;

  // Zero VT (incl. its 8-entry/row pads) and P: the PV MFMA reads K=32 with
  // only s<16 ever written -- uninitialized LDS there is 0*NaN = NaN poison.
  {
    uint32_t* z = (uint32_t*)(lds + OFF_VT);
    for (int i = tid; i < (24576 + 10240) / 4; i += NTH) z[i] = 0;
  }

  // ---------------- Phase 1: LN1 -> h1 (bf16) in LDS ----------------
  {
    const int r = tid >> 2;     // 0..127
    const int seg = tid & 3;    // 64-col segment
    const float* xrow = xg + (size_t)(row0 + r) * 256 + seg * 64;
    float s = 0.f, sq = 0.f;
#pragma unroll
    for (int i = 0; i < 16; ++i) {
      float4 v = ((const float4*)xrow)[i];
      s += v.x + v.y + v.z + v.w;
      sq += v.x * v.x + v.y * v.y + v.z * v.z + v.w * v.w;
    }
    s += __shfl_xor(s, 1); s += __shfl_xor(s, 2);
    sq += __shfl_xor(sq, 1); sq += __shfl_xor(sq, 2);
    float mu = s * (1.f / 256.f);
    float var = sq * (1.f / 256.f) - mu * mu;
    float rstd = rsqrtf(var + 1e-5f);
    char* hrow = lds + OFF_H + r * 528 + seg * 128;
    const float* g1p = g1 + seg * 64;
    const float* e1p = be1 + seg * 64;
#pragma unroll
    for (int i = 0; i < 16; ++i) {
      float4 v = ((const float4*)xrow)[i];
      float4 gv = ((const float4*)g1p)[i];
      float4 bv = ((const float4*)e1p)[i];
      uint32_t p0 = (uint32_t)f2bf((v.x - mu) * rstd * gv.x + bv.x) |
                    ((uint32_t)f2bf((v.y - mu) * rstd * gv.y + bv.y) << 16);
      uint32_t p1 = (uint32_t)f2bf((v.z - mu) * rstd * gv.z + bv.z) |
                    ((uint32_t)f2bf((v.w - mu) * rstd * gv.w + bv.w) << 16);
      uint2 u; u.x = p0; u.y = p1;
      *(uint2*)(hrow + i * 8) = u;
    }
  }
  __syncthreads();

  const f32x4 zero4 = {0.f, 0.f, 0.f, 0.f};
  f32x4 yacc[4][4];   // attn@Wo accumulator -> becomes x1 -> becomes output acc
#pragma unroll
  for (int mt = 0; mt < 4; ++mt)
#pragma unroll
    for (int nt = 0; nt < 4; ++nt) yacc[mt][nt] = zero4;

  // ---------------- Phase 2: per-head QKV -> attention -> Wo ----------------
  for (int h = 0; h < 4; ++h) {
    // --- QKV GEMM: [128,256] x [256,192], wave = 4 mtiles x 3 ntiles ---
    f32x4 qa[4][3];
#pragma unroll
    for (int mt = 0; mt < 4; ++mt)
#pragma unroll
      for (int nt = 0; nt < 3; ++nt) qa[mt][nt] = zero4;
    const uint16_t* wsrc = qkvt + (size_t)h * 192 * 256;
    for (int ks = 0; ks < 8; ++ks) {
      stageB(wsrc, 256, ks * 32, 192, lds + OFF_STG, tid);
      __syncthreads();
      s16x8 af[4], bf[3];
#pragma unroll
      for (int mt = 0; mt < 4; ++mt)
        af[mt] = *(const s16x8*)(lds + OFF_H + (64 * wr + 16 * mt + l15) * 528 +
                                 (ks * 32 + quad * 8) * 2);
#pragma unroll
      for (int nt = 0; nt < 3; ++nt)
        bf[nt] = *(const s16x8*)(lds + OFF_STG + (48 * wc + 16 * nt + l15) * 80 +
                                 quad * 16);
#pragma unroll
      for (int mt = 0; mt < 4; ++mt)
#pragma unroll
        for (int nt = 0; nt < 3; ++nt)
          qa[mt][nt] = __builtin_amdgcn_mfma_f32_16x16x32_bf16(af[mt], bf[nt],
                                                               qa[mt][nt], 0, 0, 0);
      __syncthreads();
    }
    // scatter q/k/v (bf16) into attention scratch
#pragma unroll
    for (int mt = 0; mt < 4; ++mt) {
#pragma unroll
      for (int nt = 0; nt < 3; ++nt) {
        int col = 48 * wc + 16 * nt + l15;
        int comp = col >> 6, d = col & 63;
#pragma unroll
        for (int reg = 0; reg < 4; ++reg) {
          int grow = 64 * wr + 16 * mt + 4 * quad + reg;
          uint16_t v = f2bf(qa[mt][nt][reg]);
          if (comp == 0)
            *(uint16_t*)(lds + OFF_Q + grow * 144 + d * 2) = v;
          else if (comp == 1)
            *(uint16_t*)(lds + OFF_K + grow * 144 + d * 2) = v;
          else
            *(uint16_t*)(lds + OFF_VT + (grow >> 4) * 3072 + d * 48 +
                         (grow & 15) * 2) = v;
        }
      }
    }
    __syncthreads();

    // --- attention: wave = one batch element (16 tokens) ---
    {
      f32x4 sacc = zero4;
#pragma unroll
      for (int kk = 0; kk < 2; ++kk) {
        s16x8 aq = *(const s16x8*)(lds + OFF_Q + (16 * wave + l15) * 144 +
                                   (kk * 32 + quad * 8) * 2);
        s16x8 bk = *(const s16x8*)(lds + OFF_K + (16 * wave + l15) * 144 +
                                   (kk * 32 + quad * 8) * 2);
        sacc = __builtin_amdgcn_mfma_f32_16x16x32_bf16(aq, bk, sacc, 0, 0, 0);
      }
      char* pb = lds + OFF_P + wave * 1280;
#pragma unroll
      for (int reg = 0; reg < 4; ++reg) {
        int t = 4 * quad + reg, ss = l15;
        float sc = sacc[reg] * 0.0625f;           // * C^-0.5
        if (ss > t) sc = -1e30f;                  // causal mask
        float mx = sc;
#pragma unroll
        for (int d = 1; d < 16; d <<= 1) mx = fmaxf(mx, __shfl_xor(mx, d, 16));
        float e = __expf(sc - mx);
        float sm = e;
#pragma unroll
        for (int d = 1; d < 16; d <<= 1) sm += __shfl_xor(sm, d, 16);
        *(uint16_t*)(pb + t * 80 + ss * 2) = f2bf(e / sm);
      }
      // PV: A = P (K padded to 32 with zeros), B = V^T
      s16x8 ap = *(const s16x8*)(pb + l15 * 80 + quad * 16);
      f32x4 oacc[4];
#pragma unroll
      for (int nt = 0; nt < 4; ++nt) {
        s16x8 bv = *(const s16x8*)(lds + OFF_VT + wave * 3072 +
                                   (16 * nt + l15) * 48 + quad * 16);
        oacc[nt] = __builtin_amdgcn_mfma_f32_16x16x32_bf16(ap, bv, zero4, 0, 0, 0);
      }
      // attn out -> Q region (reused as Wo A-operand)
#pragma unroll
      for (int nt = 0; nt < 4; ++nt)
#pragma unroll
        for (int reg = 0; reg < 4; ++reg)
          *(uint16_t*)(lds + OFF_Q + (16 * wave + 4 * quad + reg) * 144 +
                       (16 * nt + l15) * 2) = f2bf(oacc[nt][reg]);
    }
    __syncthreads();

    // --- Wo partial: y += attn_h @ Wo[64h:64h+64, :] ---
    for (int ks = 0; ks < 2; ++ks) {
      stageB(wot, 256, h * 64 + ks * 32, 256, lds + OFF_STG, tid);
      __syncthreads();
      s16x8 af[4], bf[4];
#pragma unroll
      for (int mt = 0; mt < 4; ++mt)
        af[mt] = *(const s16x8*)(lds + OFF_Q + (64 * wr + 16 * mt + l15) * 144 +
                                 (ks * 32 + quad * 8) * 2);
#pragma unroll
      for (int nt = 0; nt < 4; ++nt)
        bf[nt] = *(const s16x8*)(lds + OFF_STG + (64 * wc + 16 * nt + l15) * 80 +
                                 quad * 16);
#pragma unroll
      for (int mt = 0; mt < 4; ++mt)
#pragma unroll
        for (int nt = 0; nt < 4; ++nt)
          yacc[mt][nt] = __builtin_amdgcn_mfma_f32_16x16x32_bf16(af[mt], bf[nt],
                                                                 yacc[mt][nt], 0, 0, 0);
      __syncthreads();
    }
  }  // head loop

  // ---------------- Phase 3: x1 = x + attn@Wo + bo (in registers) -----------
#pragma unroll
  for (int nt = 0; nt < 4; ++nt) {
    int col = 64 * wc + 16 * nt + l15;
    float bov = bo[col];
#pragma unroll
    for (int mt = 0; mt < 4; ++mt)
#pragma unroll
      for (int reg = 0; reg < 4; ++reg) {
        int grow = row0 + 64 * wr + 16 * mt + 4 * quad + reg;
        yacc[mt][nt][reg] += xg[(size_t)grow * 256 + col] + bov;
      }
  }

  // ---------------- Phase 4: LN2 -> h2 (bf16) in LDS ----------------
  {
    float* stats = (float*)(lds + OFF_STATS);
#pragma unroll
    for (int mt = 0; mt < 4; ++mt)
#pragma unroll
      for (int reg = 0; reg < 4; ++reg) {
        float ps = 0.f, pq = 0.f;
#pragma unroll
        for (int nt = 0; nt < 4; ++nt) {
          float v = yacc[mt][nt][reg];
          ps += v; pq += v * v;
        }
#pragma unroll
        for (int d = 1; d < 16; d <<= 1) {
          ps += __shfl_xor(ps, d, 16);
          pq += __shfl_xor(pq, d, 16);
        }
        if (l15 == 0) {
          int lrow = 64 * wr + 16 * mt + 4 * quad + reg;
          stats[lrow * 8 + wc] = ps;
          stats[lrow * 8 + 4 + wc] = pq;
        }
      }
    __syncthreads();
    float g2v[4], e2v[4];
#pragma unroll
    for (int nt = 0; nt < 4; ++nt) {
      int col = 64 * wc + 16 * nt + l15;
      g2v[nt] = g2[col]; e2v[nt] = be2[col];
    }
#pragma unroll
    for (int mt = 0; mt < 4; ++mt)
#pragma unroll
      for (int reg = 0; reg < 4; ++reg) {
        int lrow = 64 * wr + 16 * mt + 4 * quad + reg;
        f32x4 s0 = *(const f32x4*)(stats + lrow * 8);
        f32x4 s1 = *(const f32x4*)(stats + lrow * 8 + 4);
        float mu = (s0[0] + s0[1] + s0[2] + s0[3]) * (1.f / 256.f);
        float var = (s1[0] + s1[1] + s1[2] + s1[3]) * (1.f / 256.f) - mu * mu;
        float rstd = rsqrtf(var + 1e-5f);
#pragma unroll
        for (int nt = 0; nt < 4; ++nt) {
          float hv = (yacc[mt][nt][reg] - mu) * rstd * g2v[nt] + e2v[nt];
          *(uint16_t*)(lds + OFF_H + lrow * 528 + (64 * wc + 16 * nt + l15) * 2) =
              f2bf(hv);
        }
      }
    __syncthreads();
  }

  // ---------------- Phase 5: FF, accumulating into residual regs ------------
#pragma unroll
  for (int nt = 0; nt < 4; ++nt) {
    float b2v = b2[64 * wc + 16 * nt + l15];
#pragma unroll
    for (int mt = 0; mt < 4; ++mt)
#pragma unroll
      for (int reg = 0; reg < 4; ++reg) yacc[mt][nt][reg] += b2v;
  }
  for (int fc = 0; fc < 4; ++fc) {
    // W1 chunk: u = relu(h2 @ W1[:, 256fc:256fc+256] + b1)
    f32x4 ua[4][4];
#pragma unroll
    for (int mt = 0; mt < 4; ++mt)
#pragma unroll
      for (int nt = 0; nt < 4; ++nt) ua[mt][nt] = zero4;
    const uint16_t* w1src = w1t + (size_t)(fc * 256) * 256;
    for (int ks = 0; ks < 8; ++ks) {
      stageB(w1src, 256, ks * 32, 256, lds + OFF_STG, tid);
      __syncthreads();
      s16x8 af[4], bf[4];
#pragma unroll
      for (int mt = 0; mt < 4; ++mt)
        af[mt] = *(const s16x8*)(lds + OFF_H + (64 * wr + 16 * mt + l15) * 528 +
                                 (ks * 32 + quad * 8) * 2);
#pragma unroll
      for (int nt = 0; nt < 4; ++nt)
        bf[nt] = *(const s16x8*)(lds + OFF_STG + (64 * wc + 16 * nt + l15) * 80 +
                                 quad * 16);
#pragma unroll
      for (int mt = 0; mt < 4; ++mt)
#pragma unroll
        for (int nt = 0; nt < 4; ++nt)
          ua[mt][nt] = __builtin_amdgcn_mfma_f32_16x16x32_bf16(af[mt], bf[nt],
                                                               ua[mt][nt], 0, 0, 0);
      __syncthreads();
    }
#pragma unroll
    for (int nt = 0; nt < 4; ++nt) {
      float b1v = b1[fc * 256 + 64 * wc + 16 * nt + l15];
#pragma unroll
      for (int mt = 0; mt < 4; ++mt)
#pragma unroll
        for (int reg = 0; reg < 4; ++reg) {
          float uv = fmaxf(ua[mt][nt][reg] + b1v, 0.f);
          *(uint16_t*)(lds + OFF_U + (64 * wr + 16 * mt + 4 * quad + reg) * 528 +
                       (64 * wc + 16 * nt + l15) * 2) = f2bf(uv);
        }
    }
    __syncthreads();
    // W2 partial: out += u @ W2[256fc:256fc+256, :]
    for (int ks = 0; ks < 8; ++ks) {
      stageB(w2t, 1024, fc * 256 + ks * 32, 256, lds + OFF_STG, tid);
      __syncthreads();
      s16x8 af[4], bf[4];
#pragma unroll
      for (int mt = 0; mt < 4; ++mt)
        af[mt] = *(const s16x8*)(lds + OFF_U + (64 * wr + 16 * mt + l15) * 528 +
                                 (ks * 32 + quad * 8) * 2);
#pragma unroll
      for (int nt = 0; nt < 4; ++nt)
        bf[nt] = *(const s16x8*)(lds + OFF_STG + (64 * wc + 16 * nt + l15) * 80 +
                                 quad * 16);
#pragma unroll
      for (int mt = 0; mt < 4; ++mt)
#pragma unroll
        for (int nt = 0; nt < 4; ++nt)
          yacc[mt][nt] = __builtin_amdgcn_mfma_f32_16x16x32_bf16(af[mt], bf[nt],
                                                                 yacc[mt][nt], 0, 0, 0);
      __syncthreads();
    }
  }

  // ---------------- Phase 6: store fp32 output ----------------
#pragma unroll
  for (int mt = 0; mt < 4; ++mt)
#pragma unroll
    for (int nt = 0; nt < 4; ++nt) {
      int col = 64 * wc + 16 * nt + l15;
#pragma unroll
      for (int reg = 0; reg < 4; ++reg) {
        int grow = row0 + 64 * wr + 16 * mt + 4 * quad + reg;
        outg[(size_t)grow * 256 + col] = yacc[mt][nt][reg];
      }
    }
}

// ------------------------------- launcher ----------------------------------
extern "C" void kernel_launch(void* const* d_in, const int* in_sizes, int n_in,
                              void* d_out, int out_size, void* d_ws, size_t ws_size,
                              hipStream_t stream) {
  (void)in_sizes; (void)n_in; (void)out_size; (void)ws_size;
  const float* x   = (const float*)d_in[0];
  const float* Wq  = (const float*)d_in[1];
  const float* Wk  = (const float*)d_in[2];
  const float* Wv  = (const float*)d_in[3];
  const float* Wo  = (const float*)d_in[4];
  const float* bo  = (const float*)d_in[5];
  const float* W1  = (const float*)d_in[6];
  const float* b1  = (const float*)d_in[7];
  const float* W2  = (const float*)d_in[8];
  const float* b2  = (const float*)d_in[9];
  const float* g1  = (const float*)d_in[10];
  const float* be1 = (const float*)d_in[11];
  const float* g2  = (const float*)d_in[12];
  const float* be2 = (const float*)d_in[13];

  uint16_t* ws   = (uint16_t*)d_ws;
  uint16_t* qkvt = ws;              // 4*192*256 = 196608 bf16
  uint16_t* wot  = ws + 196608;     // 256*256   =  65536
  uint16_t* w1t  = ws + 262144;     // 1024*256  = 262144
  uint16_t* w2t  = ws + 524288;     // 256*1024  = 262144

  cvt_qkv<<<768, 256, 0, stream>>>(Wq, Wk, Wv, qkvt);
  cvt_t<<<256, 256, 0, stream>>>(Wo, wot, 256, 256);
  cvt_t<<<1024, 256, 0, stream>>>(W1, w1t, 256, 1024);
  cvt_t<<<1024, 256, 0, stream>>>(W2, w2t, 1024, 256);

  block_fused<<<1024, NTH, 0, stream>>>(x, qkvt, wot, w1t, w2t, bo, b1, b2, g1,
                                        be1, g2, be2, (float*)d_out);
}

// Round 3
// 638.168 us; speedup vs baseline: 1.1728x; 1.1728x over previous
//
#include <hip/hip_runtime.h>
#include <stdint.h>
#include <stddef.h>

// ---------------------------------------------------------------------------
// Fused pre-LN transformer block, B=8192 T=16 C=256 H=4 HS=64 FF=1024.
// bf16 MFMA (16x16x32), fp32 accumulation, fp32 residual path.
// One WG = 128 rows (8 batch elems, 1 per wave for attention), 512 thr = 8 waves.
// R3: software-pipelined B-staging (prefetch into VGPRs one stage ahead) so
//     global->LDS latency hides under MFMA+ds_read; fused 1-launch weight cvt.
// ---------------------------------------------------------------------------

#define NTH 512

using f32x4 = __attribute__((ext_vector_type(4))) float;
using s16x8 = __attribute__((ext_vector_type(8))) short;

__device__ __forceinline__ uint16_t f2bf(float f) {
  union { float f; uint32_t u; } v; v.f = f;
  uint32_t r = v.u + 0x7FFF + ((v.u >> 16) & 1);  // RNE
  return (uint16_t)(r >> 16);
}

// ---------------- fused weight conversion: f32 [K][N] -> bf16 [N][K] -------
// One launch, LDS-tiled 32x32 transpose, coalesced reads AND writes.
// blocks: [0,192) qkv (12 jobs x 16 tiles), [192,256) Wo, [256,512) W1,
//         [512,768) W2.
__global__ void cvt_all(const float* __restrict__ Wq, const float* __restrict__ Wk,
                        const float* __restrict__ Wv, const float* __restrict__ Wo,
                        const float* __restrict__ W1, const float* __restrict__ W2,
                        uint16_t* __restrict__ qkvt, uint16_t* __restrict__ wot,
                        uint16_t* __restrict__ w1t, uint16_t* __restrict__ w2t) {
  __shared__ float tile[32][33];
  int b = blockIdx.x;
  const float* src; uint16_t* dst; int K, N, kt, nt;
  if (b < 192) {
    int j = b >> 4, t = b & 15;       // j=(h,comp), t = tile in [8][2]
    int h = j / 3, comp = j % 3;
    src = (comp == 0 ? Wq : (comp == 1 ? Wk : Wv)) + h * 16384;  // [256][64]
    dst = qkvt + h * 192 * 256 + comp * 64 * 256;
    K = 256; N = 64; kt = t >> 1; nt = t & 1;
  } else if (b < 256) {
    int t = b - 192;
    src = Wo; dst = wot; K = 256; N = 256; kt = t >> 3; nt = t & 7;
  } else if (b < 512) {
    int t = b - 256;
    src = W1; dst = w1t; K = 256; N = 1024; kt = t >> 5; nt = t & 31;
  } else {
    int t = b - 512;
    src = W2; dst = w2t; K = 1024; N = 256; kt = t >> 3; nt = t & 7;
  }
  int k0 = kt * 32, n0 = nt * 32;
  int ty = threadIdx.x >> 5, tx = threadIdx.x & 31;
#pragma unroll
  for (int r = 0; r < 4; ++r)
    tile[ty + 8 * r][tx] = src[(size_t)(k0 + ty + 8 * r) * N + n0 + tx];
  __syncthreads();
#pragma unroll
  for (int r = 0; r < 4; ++r)
    dst[(size_t)(n0 + ty + 8 * r) * K + k0 + tx] = f2bf(tile[tx][ty + 8 * r]);
}

// ------------------------------ LDS layout ---------------------------------
// h buf   [128][264] bf16 stride 528B  (LN1 out h1, later LN2 out h2)
// staging [256][40]  bf16 stride 80B   (B-operand K-step tiles)
// scratch union:
//   attention: Q[128][72]b16(144B rows) K[128][72] VT[8][64][24]b16(48B rows)
//              P[8 waves][16][40]b16(80B rows)
//   LN2:       STATS[128][8] f32  (overlays P)
//   FF:        U[128][264] bf16 stride 528B (overlays whole scratch)
#define OFF_H     0
#define OFF_STG   67584
#define OFF_SCR   88064
#define OFF_Q     (OFF_SCR + 0)
#define OFF_K     (OFF_SCR + 18432)
#define OFF_VT    (OFF_SCR + 36864)
#define OFF_P     (OFF_SCR + 61440)
#define OFF_STATS (OFF_SCR + 61440)
#define OFF_U     (OFF_SCR + 0)
#define LDS_BYTES 159744

// ---------------- software-pipelined GEMM phase ----------------------------
// C[128 x 16*NT*4] += A(lds) x B(global,bf16 [n][K])^T, K-loop of NST steps
// of 32. B staged via VGPR prefetch one stage ahead -> L2 latency hidden.
// A-frag layout: m=l15, k=quad*8+j (m97-verified). Wave grid 2x4 (wr,wc).
template <int NT, int NROWS, int NST>
__device__ __forceinline__ void gemm_phase(
    char* lds, const uint16_t* __restrict__ bsrc, int bstrideK,
    int abase, int astride, f32x4 (&acc)[4][NT],
    int tid, int wr, int wc, int l15, int quad) {
  constexpr int CH = NROWS * 4;  // 16B chunks per stage
  uint4 pf0, pf1;
  {
    int i0 = tid, i1 = tid + NTH;
    pf0 = *(const uint4*)(bsrc + (size_t)(i0 >> 2) * bstrideK + (i0 & 3) * 8);
    if (CH > NTH && i1 < CH)
      pf1 = *(const uint4*)(bsrc + (size_t)(i1 >> 2) * bstrideK + (i1 & 3) * 8);
  }
#pragma unroll
  for (int ks = 0; ks < NST; ++ks) {
    __syncthreads();  // STG free (prior consumers done)
    {
      int i0 = tid, i1 = tid + NTH;
      *(uint4*)(lds + OFF_STG + (i0 >> 2) * 80 + (i0 & 3) * 16) = pf0;
      if (CH > NTH && i1 < CH)
        *(uint4*)(lds + OFF_STG + (i1 >> 2) * 80 + (i1 & 3) * 16) = pf1;
    }
    __syncthreads();  // STG ready
    if (ks + 1 < NST) {
      const uint16_t* bs = bsrc + (ks + 1) * 32;
      int i0 = tid, i1 = tid + NTH;
      pf0 = *(const uint4*)(bs + (size_t)(i0 >> 2) * bstrideK + (i0 & 3) * 8);
      if (CH > NTH && i1 < CH)
        pf1 = *(const uint4*)(bs + (size_t)(i1 >> 2) * bstrideK + (i1 & 3) * 8);
    }
    s16x8 af[4], bfr[NT];
#pragma unroll
    for (int mt = 0; mt < 4; ++mt)
      af[mt] = *(const s16x8*)(lds + abase + (64 * wr + 16 * mt + l15) * astride +
                               (ks * 32 + quad * 8) * 2);
#pragma unroll
    for (int nt = 0; nt < NT; ++nt)
      bfr[nt] = *(const s16x8*)(lds + OFF_STG +
                                (NT * 16 * wc + 16 * nt + l15) * 80 + quad * 16);
#pragma unroll
    for (int mt = 0; mt < 4; ++mt)
#pragma unroll
      for (int nt = 0; nt < NT; ++nt)
        acc[mt][nt] = __builtin_amdgcn_mfma_f32_16x16x32_bf16(af[mt], bfr[nt],
                                                              acc[mt][nt], 0, 0, 0);
  }
}

__global__ __launch_bounds__(NTH, 2) void block_fused(
    const float* __restrict__ xg,
    const uint16_t* __restrict__ qkvt, const uint16_t* __restrict__ wot,
    const uint16_t* __restrict__ w1t, const uint16_t* __restrict__ w2t,
    const float* __restrict__ bo, const float* __restrict__ b1,
    const float* __restrict__ b2, const float* __restrict__ g1,
    const float* __restrict__ be1, const float* __restrict__ g2,
    const float* __restrict__ be2, float* __restrict__ outg) {
  __shared__ __align__(16) char lds[LDS_BYTES];
  const int tid = threadIdx.x;
  const int wave = tid >> 6, lane = tid & 63;
  const int quad = lane >> 4, l15 = lane & 15;
  const int wr = wave >> 2, wc = wave & 3;   // 2x4 wave grid for GEMMs
  const int row0 = blockIdx.x * 128;

  // Zero VT (incl. row pads) and P: the PV MFMA reads K=32 with only s<16
  // ever written -- uninitialized LDS there is 0*NaN = NaN poison.
  {
    uint32_t* z = (uint32_t*)(lds + OFF_VT);
    for (int i = tid; i < (24576 + 10240) / 4; i += NTH) z[i] = 0;
  }

  // ---------------- Phase 1: LN1 -> h1 (bf16) in LDS ----------------
  {
    const int r = tid >> 2;     // 0..127
    const int seg = tid & 3;    // 64-col segment
    const float* xrow = xg + (size_t)(row0 + r) * 256 + seg * 64;
    float s = 0.f, sq = 0.f;
#pragma unroll
    for (int i = 0; i < 16; ++i) {
      float4 v = ((const float4*)xrow)[i];
      s += v.x + v.y + v.z + v.w;
      sq += v.x * v.x + v.y * v.y + v.z * v.z + v.w * v.w;
    }
    s += __shfl_xor(s, 1); s += __shfl_xor(s, 2);
    sq += __shfl_xor(sq, 1); sq += __shfl_xor(sq, 2);
    float mu = s * (1.f / 256.f);
    float var = sq * (1.f / 256.f) - mu * mu;
    float rstd = rsqrtf(var + 1e-5f);
    char* hrow = lds + OFF_H + r * 528 + seg * 128;
    const float* g1p = g1 + seg * 64;
    const float* e1p = be1 + seg * 64;
#pragma unroll
    for (int i = 0; i < 16; ++i) {
      float4 v = ((const float4*)xrow)[i];
      float4 gv = ((const float4*)g1p)[i];
      float4 bv = ((const float4*)e1p)[i];
      uint32_t p0 = (uint32_t)f2bf((v.x - mu) * rstd * gv.x + bv.x) |
                    ((uint32_t)f2bf((v.y - mu) * rstd * gv.y + bv.y) << 16);
      uint32_t p1 = (uint32_t)f2bf((v.z - mu) * rstd * gv.z + bv.z) |
                    ((uint32_t)f2bf((v.w - mu) * rstd * gv.w + bv.w) << 16);
      uint2 u; u.x = p0; u.y = p1;
      *(uint2*)(hrow + i * 8) = u;
    }
  }
  __syncthreads();

  const f32x4 zero4 = {0.f, 0.f, 0.f, 0.f};
  f32x4 yacc[4][4];   // attn@Wo accumulator -> becomes x1 -> becomes output acc
#pragma unroll
  for (int mt = 0; mt < 4; ++mt)
#pragma unroll
    for (int nt = 0; nt < 4; ++nt) yacc[mt][nt] = zero4;

  // ---------------- Phase 2: per-head QKV -> attention -> Wo ----------------
  for (int h = 0; h < 4; ++h) {
    // --- QKV GEMM: [128,256] x [256,192], wave = 4 mtiles x 3 ntiles ---
    f32x4 qa[4][3];
#pragma unroll
    for (int mt = 0; mt < 4; ++mt)
#pragma unroll
      for (int nt = 0; nt < 3; ++nt) qa[mt][nt] = zero4;
    gemm_phase<3, 192, 8>(lds, qkvt + (size_t)h * 192 * 256, 256,
                          OFF_H, 528, qa, tid, wr, wc, l15, quad);
    // scatter q/k/v (bf16) into attention scratch
#pragma unroll
    for (int mt = 0; mt < 4; ++mt) {
#pragma unroll
      for (int nt = 0; nt < 3; ++nt) {
        int col = 48 * wc + 16 * nt + l15;
        int comp = col >> 6, d = col & 63;
#pragma unroll
        for (int reg = 0; reg < 4; ++reg) {
          int grow = 64 * wr + 16 * mt + 4 * quad + reg;
          uint16_t v = f2bf(qa[mt][nt][reg]);
          if (comp == 0)
            *(uint16_t*)(lds + OFF_Q + grow * 144 + d * 2) = v;
          else if (comp == 1)
            *(uint16_t*)(lds + OFF_K + grow * 144 + d * 2) = v;
          else
            *(uint16_t*)(lds + OFF_VT + (grow >> 4) * 3072 + d * 48 +
                         (grow & 15) * 2) = v;
        }
      }
    }
    __syncthreads();

    // --- attention: wave = one batch element (16 tokens) ---
    {
      f32x4 sacc = zero4;
#pragma unroll
      for (int kk = 0; kk < 2; ++kk) {
        s16x8 aq = *(const s16x8*)(lds + OFF_Q + (16 * wave + l15) * 144 +
                                   (kk * 32 + quad * 8) * 2);
        s16x8 bk = *(const s16x8*)(lds + OFF_K + (16 * wave + l15) * 144 +
                                   (kk * 32 + quad * 8) * 2);
        sacc = __builtin_amdgcn_mfma_f32_16x16x32_bf16(aq, bk, sacc, 0, 0, 0);
      }
      char* pb = lds + OFF_P + wave * 1280;
#pragma unroll
      for (int reg = 0; reg < 4; ++reg) {
        int t = 4 * quad + reg, ss = l15;
        float sc = sacc[reg] * 0.0625f;           // * C^-0.5
        if (ss > t) sc = -1e30f;                  // causal mask
        float mx = sc;
#pragma unroll
        for (int d = 1; d < 16; d <<= 1) mx = fmaxf(mx, __shfl_xor(mx, d, 16));
        float e = __expf(sc - mx);
        float sm = e;
#pragma unroll
        for (int d = 1; d < 16; d <<= 1) sm += __shfl_xor(sm, d, 16);
        *(uint16_t*)(pb + t * 80 + ss * 2) = f2bf(e / sm);
      }
      // PV: A = P (K padded to 32 with zeros), B = V^T
      s16x8 ap = *(const s16x8*)(pb + l15 * 80 + quad * 16);
      f32x4 oacc[4];
#pragma unroll
      for (int nt = 0; nt < 4; ++nt) {
        s16x8 bv = *(const s16x8*)(lds + OFF_VT + wave * 3072 +
                                   (16 * nt + l15) * 48 + quad * 16);
        oacc[nt] = __builtin_amdgcn_mfma_f32_16x16x32_bf16(ap, bv, zero4, 0, 0, 0);
      }
      // attn out -> Q region (reused as Wo A-operand)
#pragma unroll
      for (int nt = 0; nt < 4; ++nt)
#pragma unroll
        for (int reg = 0; reg < 4; ++reg)
          *(uint16_t*)(lds + OFF_Q + (16 * wave + 4 * quad + reg) * 144 +
                       (16 * nt + l15) * 2) = f2bf(oacc[nt][reg]);
    }
    __syncthreads();

    // --- Wo partial: y += attn_h @ Wo[64h:64h+64, :] ---
    gemm_phase<4, 256, 2>(lds, wot + h * 64, 256, OFF_Q, 144, yacc,
                          tid, wr, wc, l15, quad);
    __syncthreads();  // STG + Q consumed before next head's staging/scatter
  }  // head loop

  // ---------------- Phase 3: x1 = x + attn@Wo + bo (in registers) -----------
#pragma unroll
  for (int nt = 0; nt < 4; ++nt) {
    int col = 64 * wc + 16 * nt + l15;
    float bov = bo[col];
#pragma unroll
    for (int mt = 0; mt < 4; ++mt)
#pragma unroll
      for (int reg = 0; reg < 4; ++reg) {
        int grow = row0 + 64 * wr + 16 * mt + 4 * quad + reg;
        yacc[mt][nt][reg] += xg[(size_t)grow * 256 + col] + bov;
      }
  }

  // ---------------- Phase 4: LN2 -> h2 (bf16) in LDS ----------------
  {
    float* stats = (float*)(lds + OFF_STATS);
#pragma unroll
    for (int mt = 0; mt < 4; ++mt)
#pragma unroll
      for (int reg = 0; reg < 4; ++reg) {
        float ps = 0.f, pq = 0.f;
#pragma unroll
        for (int nt = 0; nt < 4; ++nt) {
          float v = yacc[mt][nt][reg];
          ps += v; pq += v * v;
        }
#pragma unroll
        for (int d = 1; d < 16; d <<= 1) {
          ps += __shfl_xor(ps, d, 16);
          pq += __shfl_xor(pq, d, 16);
        }
        if (l15 == 0) {
          int lrow = 64 * wr + 16 * mt + 4 * quad + reg;
          stats[lrow * 8 + wc] = ps;
          stats[lrow * 8 + 4 + wc] = pq;
        }
      }
    __syncthreads();
    float g2v[4], e2v[4];
#pragma unroll
    for (int nt = 0; nt < 4; ++nt) {
      int col = 64 * wc + 16 * nt + l15;
      g2v[nt] = g2[col]; e2v[nt] = be2[col];
    }
#pragma unroll
    for (int mt = 0; mt < 4; ++mt)
#pragma unroll
      for (int reg = 0; reg < 4; ++reg) {
        int lrow = 64 * wr + 16 * mt + 4 * quad + reg;
        f32x4 s0 = *(const f32x4*)(stats + lrow * 8);
        f32x4 s1 = *(const f32x4*)(stats + lrow * 8 + 4);
        float mu = (s0[0] + s0[1] + s0[2] + s0[3]) * (1.f / 256.f);
        float var = (s1[0] + s1[1] + s1[2] + s1[3]) * (1.f / 256.f) - mu * mu;
        float rstd = rsqrtf(var + 1e-5f);
#pragma unroll
        for (int nt = 0; nt < 4; ++nt) {
          float hv = (yacc[mt][nt][reg] - mu) * rstd * g2v[nt] + e2v[nt];
          *(uint16_t*)(lds + OFF_H + lrow * 528 + (64 * wc + 16 * nt + l15) * 2) =
              f2bf(hv);
        }
      }
    __syncthreads();
  }

  // ---------------- Phase 5: FF, accumulating into residual regs ------------
#pragma unroll
  for (int nt = 0; nt < 4; ++nt) {
    float b2v = b2[64 * wc + 16 * nt + l15];
#pragma unroll
    for (int mt = 0; mt < 4; ++mt)
#pragma unroll
      for (int reg = 0; reg < 4; ++reg) yacc[mt][nt][reg] += b2v;
  }
  for (int fc = 0; fc < 4; ++fc) {
    // W1 chunk: u = relu(h2 @ W1[:, 256fc:256fc+256] + b1)
    f32x4 ua[4][4];
#pragma unroll
    for (int mt = 0; mt < 4; ++mt)
#pragma unroll
      for (int nt = 0; nt < 4; ++nt) ua[mt][nt] = zero4;
    gemm_phase<4, 256, 8>(lds, w1t + (size_t)(fc * 256) * 256, 256,
                          OFF_H, 528, ua, tid, wr, wc, l15, quad);
    __syncthreads();  // last-stage STG reads done before U overwrites scratch
#pragma unroll
    for (int nt = 0; nt < 4; ++nt) {
      float b1v = b1[fc * 256 + 64 * wc + 16 * nt + l15];
#pragma unroll
      for (int mt = 0; mt < 4; ++mt)
#pragma unroll
        for (int reg = 0; reg < 4; ++reg) {
          float uv = fmaxf(ua[mt][nt][reg] + b1v, 0.f);
          *(uint16_t*)(lds + OFF_U + (64 * wr + 16 * mt + 4 * quad + reg) * 528 +
                       (64 * wc + 16 * nt + l15) * 2) = f2bf(uv);
        }
    }
    __syncthreads();
    // W2 partial: out += u @ W2[256fc:256fc+256, :]
    gemm_phase<4, 256, 8>(lds, w2t + fc * 256, 1024, OFF_U, 528, yacc,
                          tid, wr, wc, l15, quad);
    __syncthreads();  // U fully consumed before next fc overwrites it
  }

  // ---------------- Phase 6: store fp32 output ----------------
#pragma unroll
  for (int mt = 0; mt < 4; ++mt)
#pragma unroll
    for (int nt = 0; nt < 4; ++nt) {
      int col = 64 * wc + 16 * nt + l15;
#pragma unroll
      for (int reg = 0; reg < 4; ++reg) {
        int grow = row0 + 64 * wr + 16 * mt + 4 * quad + reg;
        outg[(size_t)grow * 256 + col] = yacc[mt][nt][reg];
      }
    }
}

// ------------------------------- launcher ----------------------------------
extern "C" void kernel_launch(void* const* d_in, const int* in_sizes, int n_in,
                              void* d_out, int out_size, void* d_ws, size_t ws_size,
                              hipStream_t stream) {
  (void)in_sizes; (void)n_in; (void)out_size; (void)ws_size;
  const float* x   = (const float*)d_in[0];
  const float* Wq  = (const float*)d_in[1];
  const float* Wk  = (const float*)d_in[2];
  const float* Wv  = (const float*)d_in[3];
  const float* Wo  = (const float*)d_in[4];
  const float* bo  = (const float*)d_in[5];
  const float* W1  = (const float*)d_in[6];
  const float* b1  = (const float*)d_in[7];
  const float* W2  = (const float*)d_in[8];
  const float* b2  = (const float*)d_in[9];
  const float* g1  = (const float*)d_in[10];
  const float* be1 = (const float*)d_in[11];
  const float* g2  = (const float*)d_in[12];
  const float* be2 = (const float*)d_in[13];

  uint16_t* ws   = (uint16_t*)d_ws;
  uint16_t* qkvt = ws;              // 4*192*256 = 196608 bf16
  uint16_t* wot  = ws + 196608;     // 256*256   =  65536
  uint16_t* w1t  = ws + 262144;     // 1024*256  = 262144
  uint16_t* w2t  = ws + 524288;     // 256*1024  = 262144

  cvt_all<<<768, 256, 0, stream>>>(Wq, Wk, Wv, Wo, W1, W2, qkvt, wot, w1t, w2t);

  block_fused<<<1024, NTH, 0, stream>>>(x, qkvt, wot, w1t, w2t, bo, b1, b2, g1,
                                        be1, g2, be2, (float*)d_out);
}